// Round 1
// baseline (1638.716 us; speedup 1.0000x reference)
//
#include <hip/hip_runtime.h>

#define HIDDEN 64

// ---------------- CSR build ----------------

__global__ void k_hist(const int* __restrict__ rows, int* __restrict__ cnt, int nnz) {
    int i = blockIdx.x * blockDim.x + threadIdx.x;
    if (i < nnz) atomicAdd(&cnt[rows[i]], 1);
}

// Single-block, thread-coarse exclusive scan: cnt[0..n) -> off[0..n], off[n]=total
__global__ void __launch_bounds__(1024) k_scan(const int* __restrict__ cnt,
                                               int* __restrict__ off, int n) {
    __shared__ int sums[1024];
    int t = threadIdx.x;
    int chunk = (n + 1023) / 1024;
    int begin = t * chunk;
    int end = begin + chunk; if (end > n) end = n; if (begin > n) begin = n;
    int s = 0;
    for (int i = begin; i < end; ++i) s += cnt[i];
    sums[t] = s;
    __syncthreads();
    // Hillis-Steele inclusive scan over 1024 partials
    for (int d = 1; d < 1024; d <<= 1) {
        int v = (t >= d) ? sums[t - d] : 0;
        __syncthreads();
        sums[t] += v;
        __syncthreads();
    }
    int run = sums[t] - s;  // exclusive prefix for this thread's chunk
    for (int i = begin; i < end; ++i) { off[i] = run; run += cnt[i]; }
    if (t == 1023) off[n] = sums[1023];
}

__global__ void k_scatter(const int* __restrict__ rows, const int* __restrict__ cols,
                          const float* __restrict__ vals, const int* __restrict__ off,
                          int* __restrict__ cur, int* __restrict__ scol,
                          float* __restrict__ sval, int nnz) {
    int i = blockIdx.x * blockDim.x + threadIdx.x;
    if (i >= nnz) return;
    int r = rows[i];
    int p = off[r] + atomicAdd(&cur[r], 1);
    scol[p] = cols[i];
    sval[p] = vals[i];
}

// ---------------- SpMM: one wave (64 lanes) per row, lane = dim ----------------

__global__ void __launch_bounds__(256) k_spmm(const int* __restrict__ off,
                                              const int* __restrict__ scol,
                                              const float* __restrict__ sval,
                                              const float* __restrict__ x,
                                              float* __restrict__ y, int n) {
    int row  = (int)((blockIdx.x * blockDim.x + threadIdx.x) >> 6);
    int lane = threadIdx.x & 63;
    if (row >= n) return;
    int start = off[row], end = off[row + 1];
    float acc = 0.f;
    for (int j0 = start; j0 < end; j0 += 64) {
        int m = end - j0; if (m > 64) m = 64;
        int   c = 0;
        float v = 0.f;
        if (lane < m) { c = scol[j0 + lane]; v = sval[j0 + lane]; }
        for (int k = 0; k < m; ++k) {
            int   ck = __shfl(c, k);
            float vk = __shfl(v, k);
            acc += vk * x[(size_t)ck * HIDDEN + lane];
        }
    }
    y[(size_t)row * HIDDEN + lane] = acc;
}

// ---------------- per-batch gather accumulate ----------------

__global__ void __launch_bounds__(256) k_gather_add(const float* __restrict__ e,
                                                    const int* __restrict__ user,
                                                    const int* __restrict__ pos,
                                                    const int* __restrict__ neg,
                                                    int batch, float* __restrict__ acc,
                                                    int init) {
    int row  = (int)((blockIdx.x * blockDim.x + threadIdx.x) >> 6);
    int lane = threadIdx.x & 63;
    if (row >= 3 * batch) return;
    int which = row / batch, i = row - which * batch;
    const int* sel = (which == 0) ? user : (which == 1 ? pos : neg);
    int s = sel[i];
    float v = e[(size_t)s * HIDDEN + lane];
    size_t o = (size_t)row * HIDDEN + lane;
    if (init) acc[o] = v; else acc[o] += v;
}

// ---------------- loss: wave per batch element ----------------

__global__ void __launch_bounds__(256) k_loss(const float* __restrict__ acc, int batch,
                                              float* __restrict__ out) {
    int i    = (int)((blockIdx.x * blockDim.x + threadIdx.x) >> 6);
    int lane = threadIdx.x & 63;
    if (i >= batch) return;
    float u = acc[(size_t)i * HIDDEN + lane] * 0.25f;
    float p = acc[(size_t)(i + batch) * HIDDEN + lane] * 0.25f;
    float nn = acc[(size_t)(i + 2 * batch) * HIDDEN + lane] * 0.25f;
    float sp = u * p, sn = u * nn;
    for (int d = 32; d > 0; d >>= 1) {
        sp += __shfl_down(sp, d);
        sn += __shfl_down(sn, d);
    }
    if (lane == 0) {
        float z = sn - sp;  // loss = softplus(-(sp-sn))
        float loss = fmaxf(z, 0.f) + log1pf(expf(-fabsf(z)));
        atomicAdd(out, loss);
    }
}

// ---------------- orchestration ----------------

extern "C" void kernel_launch(void* const* d_in, const int* in_sizes, int n_in,
                              void* d_out, int out_size, void* d_ws, size_t ws_size,
                              hipStream_t stream) {
    (void)n_in; (void)out_size; (void)ws_size;
    const float* emb  = (const float*)d_in[0];
    const float* vals = (const float*)d_in[1];
    const int*   rows = (const int*)d_in[2];
    const int*   cols = (const int*)d_in[3];
    const int*   user = (const int*)d_in[4];
    const int*   pos  = (const int*)d_in[5];
    const int*   neg  = (const int*)d_in[6];

    const int n     = in_sizes[0] / HIDDEN;   // 150000
    const int nnz   = in_sizes[1];            // 4.8M
    const int batch = in_sizes[4];            // 4096

    auto align256 = [](size_t x) { return (x + 255) & ~(size_t)255; };
    char* w = (char*)d_ws;
    int*   cnt  = (int*)w;   w += align256(sizeof(int)   * (size_t)n);
    int*   off  = (int*)w;   w += align256(sizeof(int)   * (size_t)(n + 1));
    int*   scol = (int*)w;   w += align256(sizeof(int)   * (size_t)nnz);
    float* sval = (float*)w; w += align256(sizeof(float) * (size_t)nnz);
    float* e0   = (float*)w; w += align256(sizeof(float) * (size_t)n * HIDDEN);
    float* e1   = (float*)w; w += align256(sizeof(float) * (size_t)n * HIDDEN);
    float* acc  = (float*)w; w += align256(sizeof(float) * (size_t)3 * batch * HIDDEN);

    float* out = (float*)d_out;

    const int B = 256;
    dim3 blk(B);
    int g_nnz   = (nnz + B - 1) / B;
    int g_spmm  = (n + 3) / 4;            // 4 waves/block, 1 row/wave
    int g_gath  = (3 * batch + 3) / 4;
    int g_loss  = (batch + 3) / 4;

    // CSR build
    hipMemsetAsync(cnt, 0, sizeof(int) * (size_t)n, stream);
    k_hist<<<g_nnz, blk, 0, stream>>>(rows, cnt, nnz);
    k_scan<<<1, 1024, 0, stream>>>(cnt, off, n);
    hipMemsetAsync(cnt, 0, sizeof(int) * (size_t)n, stream);  // reuse as cursor
    k_scatter<<<g_nnz, blk, 0, stream>>>(rows, cols, vals, off, cnt, scol, sval, nnz);

    hipMemsetAsync(out, 0, sizeof(float), stream);

    // layer 0
    k_gather_add<<<g_gath, blk, 0, stream>>>(emb, user, pos, neg, batch, acc, 1);
    // layer 1
    k_spmm<<<g_spmm, blk, 0, stream>>>(off, scol, sval, emb, e0, n);
    k_gather_add<<<g_gath, blk, 0, stream>>>(e0, user, pos, neg, batch, acc, 0);
    // layer 2
    k_spmm<<<g_spmm, blk, 0, stream>>>(off, scol, sval, e0, e1, n);
    k_gather_add<<<g_gath, blk, 0, stream>>>(e1, user, pos, neg, batch, acc, 0);
    // layer 3
    k_spmm<<<g_spmm, blk, 0, stream>>>(off, scol, sval, e1, e0, n);
    k_gather_add<<<g_gath, blk, 0, stream>>>(e0, user, pos, neg, batch, acc, 0);

    k_loss<<<g_loss, blk, 0, stream>>>(acc, batch, out);
}

// Round 2
// 1134.215 us; speedup vs baseline: 1.4448x; 1.4448x over previous
//
#include <hip/hip_runtime.h>

#define HIDDEN 64

// ---------------- CSR build ----------------

// histogram + per-entry rank (rank stored coalesced; removes atomics from scatter)
__global__ void k_hist(const int* __restrict__ rows, int* __restrict__ cnt,
                       int* __restrict__ rank, int nnz) {
    int i = blockIdx.x * blockDim.x + threadIdx.x;
    if (i < nnz) rank[i] = atomicAdd(&cnt[rows[i]], 1);
}

// Single-block, thread-coarse exclusive scan: cnt[0..n) -> off[0..n], off[n]=total
__global__ void __launch_bounds__(1024) k_scan(const int* __restrict__ cnt,
                                               int* __restrict__ off, int n) {
    __shared__ int sums[1024];
    int t = threadIdx.x;
    int chunk = (n + 1023) / 1024;
    int begin = t * chunk;
    int end = begin + chunk; if (end > n) end = n; if (begin > n) begin = n;
    int s = 0;
    for (int i = begin; i < end; ++i) s += cnt[i];
    sums[t] = s;
    __syncthreads();
    for (int d = 1; d < 1024; d <<= 1) {
        int v = (t >= d) ? sums[t - d] : 0;
        __syncthreads();
        sums[t] += v;
        __syncthreads();
    }
    int run = sums[t] - s;
    for (int i = begin; i < end; ++i) { off[i] = run; run += cnt[i]; }
    if (t == 1023) off[n] = sums[1023];
}

// packed scatter: one 8B store per nnz, no atomics
__global__ void k_scatter(const int* __restrict__ rows, const int* __restrict__ cols,
                          const float* __restrict__ vals, const int* __restrict__ off,
                          const int* __restrict__ rank, int2* __restrict__ pack, int nnz) {
    int i = blockIdx.x * blockDim.x + threadIdx.x;
    if (i >= nnz) return;
    int r = rows[i];
    int p = off[r] + rank[i];
    pack[p] = make_int2(cols[i], __float_as_int(vals[i]));
}

// ---------------- SpMM: one wave (64 lanes) per row, lane = dim ----------------

__global__ void __launch_bounds__(256) k_spmm(const int* __restrict__ off,
                                              const int2* __restrict__ pack,
                                              const float* __restrict__ x,
                                              float* __restrict__ y, int n) {
    int row  = (int)((blockIdx.x * blockDim.x + threadIdx.x) >> 6);
    int lane = threadIdx.x & 63;
    if (row >= n) return;
    int start = off[row], end = off[row + 1];
    float acc = 0.f;
    for (int j0 = start; j0 < end; j0 += 64) {
        int m = end - j0; if (m > 64) m = 64;
        int   c = 0;
        float v = 0.f;
        if (lane < m) {
            int2 cv = pack[j0 + lane];
            c = cv.x;
            v = __int_as_float(cv.y);
        }
        for (int k = 0; k < m; ++k) {
            int   ck = __shfl(c, k);
            float vk = __shfl(v, k);
            acc += vk * x[(size_t)ck * HIDDEN + lane];
        }
    }
    y[(size_t)row * HIDDEN + lane] = acc;
}

// fused selective SpMM for the final layer: one wave per batch position,
// computes (A x)[sel[i]] and accumulates into acc directly.
__global__ void __launch_bounds__(256) k_spmm_batch(const int* __restrict__ off,
                                                    const int2* __restrict__ pack,
                                                    const float* __restrict__ x,
                                                    const int* __restrict__ user,
                                                    const int* __restrict__ pos,
                                                    const int* __restrict__ neg,
                                                    int batch, float* __restrict__ acc) {
    int slot = (int)((blockIdx.x * blockDim.x + threadIdx.x) >> 6);
    int lane = threadIdx.x & 63;
    if (slot >= 3 * batch) return;
    int which = slot / batch, i = slot - which * batch;
    const int* sel = (which == 0) ? user : (which == 1 ? pos : neg);
    int row = sel[i];
    int start = off[row], end = off[row + 1];
    float a = 0.f;
    for (int j0 = start; j0 < end; j0 += 64) {
        int m = end - j0; if (m > 64) m = 64;
        int   c = 0;
        float v = 0.f;
        if (lane < m) {
            int2 cv = pack[j0 + lane];
            c = cv.x;
            v = __int_as_float(cv.y);
        }
        for (int k = 0; k < m; ++k) {
            int   ck = __shfl(c, k);
            float vk = __shfl(v, k);
            a += vk * x[(size_t)ck * HIDDEN + lane];
        }
    }
    acc[(size_t)slot * HIDDEN + lane] += a;
}

// ---------------- per-batch gather accumulate ----------------

__global__ void __launch_bounds__(256) k_gather_add(const float* __restrict__ e,
                                                    const int* __restrict__ user,
                                                    const int* __restrict__ pos,
                                                    const int* __restrict__ neg,
                                                    int batch, float* __restrict__ acc,
                                                    int init) {
    int row  = (int)((blockIdx.x * blockDim.x + threadIdx.x) >> 6);
    int lane = threadIdx.x & 63;
    if (row >= 3 * batch) return;
    int which = row / batch, i = row - which * batch;
    const int* sel = (which == 0) ? user : (which == 1 ? pos : neg);
    int s = sel[i];
    float v = e[(size_t)s * HIDDEN + lane];
    size_t o = (size_t)row * HIDDEN + lane;
    if (init) acc[o] = v; else acc[o] += v;
}

// ---------------- loss: wave per batch element ----------------

__global__ void __launch_bounds__(256) k_loss(const float* __restrict__ acc, int batch,
                                              float* __restrict__ out) {
    int i    = (int)((blockIdx.x * blockDim.x + threadIdx.x) >> 6);
    int lane = threadIdx.x & 63;
    if (i >= batch) return;
    float u = acc[(size_t)i * HIDDEN + lane] * 0.25f;
    float p = acc[(size_t)(i + batch) * HIDDEN + lane] * 0.25f;
    float nn = acc[(size_t)(i + 2 * batch) * HIDDEN + lane] * 0.25f;
    float sp = u * p, sn = u * nn;
    for (int d = 32; d > 0; d >>= 1) {
        sp += __shfl_down(sp, d);
        sn += __shfl_down(sn, d);
    }
    if (lane == 0) {
        float z = sn - sp;  // loss = softplus(-(sp-sn))
        float loss = fmaxf(z, 0.f) + log1pf(expf(-fabsf(z)));
        atomicAdd(out, loss);
    }
}

// ---------------- orchestration ----------------

extern "C" void kernel_launch(void* const* d_in, const int* in_sizes, int n_in,
                              void* d_out, int out_size, void* d_ws, size_t ws_size,
                              hipStream_t stream) {
    (void)n_in; (void)out_size; (void)ws_size;
    const float* emb  = (const float*)d_in[0];
    const float* vals = (const float*)d_in[1];
    const int*   rows = (const int*)d_in[2];
    const int*   cols = (const int*)d_in[3];
    const int*   user = (const int*)d_in[4];
    const int*   pos  = (const int*)d_in[5];
    const int*   neg  = (const int*)d_in[6];

    const int n     = in_sizes[0] / HIDDEN;   // 150000
    const int nnz   = in_sizes[1];            // 4.8M
    const int batch = in_sizes[4];            // 4096

    auto align256 = [](size_t x) { return (x + 255) & ~(size_t)255; };
    char* w = (char*)d_ws;
    int*   cnt  = (int*)w;   w += align256(sizeof(int)  * (size_t)n);
    int*   off  = (int*)w;   w += align256(sizeof(int)  * (size_t)(n + 1));
    int2*  pack = (int2*)w;  w += align256(sizeof(int2) * (size_t)nnz);
    float* e0   = (float*)w; w += align256(sizeof(float) * (size_t)n * HIDDEN);
    float* e1   = (float*)w; w += align256(sizeof(float) * (size_t)n * HIDDEN);
    float* acc  = (float*)w; w += align256(sizeof(float) * (size_t)3 * batch * HIDDEN);
    // rank is only live during the CSR build; e1 is only written after it.
    int*   rank = (int*)e1;

    float* out = (float*)d_out;

    const int B = 256;
    dim3 blk(B);
    int g_nnz  = (nnz + B - 1) / B;
    int g_spmm = (n + 3) / 4;            // 4 waves/block, 1 row/wave
    int g_gath = (3 * batch + 3) / 4;
    int g_loss = (batch + 3) / 4;

    // CSR build
    hipMemsetAsync(cnt, 0, sizeof(int) * (size_t)n, stream);
    k_hist<<<g_nnz, blk, 0, stream>>>(rows, cnt, rank, nnz);
    k_scan<<<1, 1024, 0, stream>>>(cnt, off, n);
    k_scatter<<<g_nnz, blk, 0, stream>>>(rows, cols, vals, off, rank, pack, nnz);

    hipMemsetAsync(out, 0, sizeof(float), stream);

    // layer 0
    k_gather_add<<<g_gath, blk, 0, stream>>>(emb, user, pos, neg, batch, acc, 1);
    // layer 1
    k_spmm<<<g_spmm, blk, 0, stream>>>(off, pack, emb, e0, n);
    k_gather_add<<<g_gath, blk, 0, stream>>>(e0, user, pos, neg, batch, acc, 0);
    // layer 2
    k_spmm<<<g_spmm, blk, 0, stream>>>(off, pack, e0, e1, n);
    k_gather_add<<<g_gath, blk, 0, stream>>>(e1, user, pos, neg, batch, acc, 0);
    // layer 3 (fused selective SpMM + accumulate)
    k_spmm_batch<<<g_gath, blk, 0, stream>>>(off, pack, e1, user, pos, neg, batch, acc);

    k_loss<<<g_loss, blk, 0, stream>>>(acc, batch, out);
}

// Round 3
// 899.921 us; speedup vs baseline: 1.8210x; 1.2603x over previous
//
#include <hip/hip_runtime.h>

#define HIDDEN 64

typedef unsigned int uint;
typedef unsigned short ushort16;

__device__ __forceinline__ ushort f2bf(float f) {
    uint u = __float_as_uint(f);
    u = (u + 0x7FFFu + ((u >> 16) & 1u)) >> 16;   // round-to-nearest-even
    return (ushort)u;
}
__device__ __forceinline__ float bf2f(ushort h) {
    return __uint_as_float(((uint)h) << 16);
}

// ---------------- fp32 -> bf16 table conversion ----------------

__global__ void __launch_bounds__(256) k_f2bf(const float4* __restrict__ src,
                                              ushort* __restrict__ dst, int n4) {
    int i = blockIdx.x * blockDim.x + threadIdx.x;
    if (i >= n4) return;
    float4 f = src[i];
    ushort4 o;
    o.x = f2bf(f.x); o.y = f2bf(f.y); o.z = f2bf(f.z); o.w = f2bf(f.w);
    ((ushort4*)dst)[i] = o;
}

// ---------------- CSR build ----------------

__global__ void k_hist(const int* __restrict__ rows, int* __restrict__ cnt,
                       int* __restrict__ rank, int nnz) {
    int i = blockIdx.x * blockDim.x + threadIdx.x;
    if (i < nnz) rank[i] = atomicAdd(&cnt[rows[i]], 1);
}

__global__ void __launch_bounds__(1024) k_scan(const int* __restrict__ cnt,
                                               int* __restrict__ off, int n) {
    __shared__ int sums[1024];
    int t = threadIdx.x;
    int chunk = (n + 1023) / 1024;
    int begin = t * chunk;
    int end = begin + chunk; if (end > n) end = n; if (begin > n) begin = n;
    int s = 0;
    for (int i = begin; i < end; ++i) s += cnt[i];
    sums[t] = s;
    __syncthreads();
    for (int d = 1; d < 1024; d <<= 1) {
        int v = (t >= d) ? sums[t - d] : 0;
        __syncthreads();
        sums[t] += v;
        __syncthreads();
    }
    int run = sums[t] - s;
    for (int i = begin; i < end; ++i) { off[i] = run; run += cnt[i]; }
    if (t == 1023) off[n] = sums[1023];
}

__global__ void k_scatter(const int* __restrict__ rows, const int* __restrict__ cols,
                          const float* __restrict__ vals, const int* __restrict__ off,
                          const int* __restrict__ rank, int2* __restrict__ pack, int nnz) {
    int i = blockIdx.x * blockDim.x + threadIdx.x;
    if (i >= nnz) return;
    int r = rows[i];
    int p = off[r] + rank[i];
    pack[p] = make_int2(cols[i], __float_as_int(vals[i]));
}

// ---------------- SpMM (bf16 x, bf16 y, fp32 accumulate) ----------------

__global__ void __launch_bounds__(256) k_spmm(const int* __restrict__ off,
                                              const int2* __restrict__ pack,
                                              const ushort* __restrict__ x,
                                              ushort* __restrict__ y, int n) {
    int row  = (int)((blockIdx.x * blockDim.x + threadIdx.x) >> 6);
    int lane = threadIdx.x & 63;
    if (row >= n) return;
    int start = off[row], end = off[row + 1];
    float acc0 = 0.f, acc1 = 0.f;
    for (int j0 = start; j0 < end; j0 += 64) {
        int m = end - j0; if (m > 64) m = 64;
        int   c = 0;
        float v = 0.f;
        if (lane < m) {
            int2 cv = pack[j0 + lane];
            c = cv.x;
            v = __int_as_float(cv.y);
        }
        int k = 0;
        #pragma unroll 4
        for (; k + 1 < m; k += 2) {
            int   c0 = __shfl(c, k);     float v0 = __shfl(v, k);
            int   c1 = __shfl(c, k + 1); float v1 = __shfl(v, k + 1);
            acc0 += v0 * bf2f(x[(size_t)c0 * HIDDEN + lane]);
            acc1 += v1 * bf2f(x[(size_t)c1 * HIDDEN + lane]);
        }
        if (k < m) {
            int ck = __shfl(c, k); float vk = __shfl(v, k);
            acc0 += vk * bf2f(x[(size_t)ck * HIDDEN + lane]);
        }
    }
    y[(size_t)row * HIDDEN + lane] = f2bf(acc0 + acc1);
}

// final layer fused: SpMM restricted to batch rows, accumulate fp32 into acc
__global__ void __launch_bounds__(256) k_spmm_batch(const int* __restrict__ off,
                                                    const int2* __restrict__ pack,
                                                    const ushort* __restrict__ x,
                                                    const int* __restrict__ user,
                                                    const int* __restrict__ pos,
                                                    const int* __restrict__ neg,
                                                    int batch, float* __restrict__ acc) {
    int slot = (int)((blockIdx.x * blockDim.x + threadIdx.x) >> 6);
    int lane = threadIdx.x & 63;
    if (slot >= 3 * batch) return;
    int which = slot / batch, i = slot - which * batch;
    const int* sel = (which == 0) ? user : (which == 1 ? pos : neg);
    int row = sel[i];
    int start = off[row], end = off[row + 1];
    float a0 = 0.f, a1 = 0.f;
    for (int j0 = start; j0 < end; j0 += 64) {
        int m = end - j0; if (m > 64) m = 64;
        int   c = 0;
        float v = 0.f;
        if (lane < m) {
            int2 cv = pack[j0 + lane];
            c = cv.x;
            v = __int_as_float(cv.y);
        }
        int k = 0;
        #pragma unroll 4
        for (; k + 1 < m; k += 2) {
            int   c0 = __shfl(c, k);     float v0 = __shfl(v, k);
            int   c1 = __shfl(c, k + 1); float v1 = __shfl(v, k + 1);
            a0 += v0 * bf2f(x[(size_t)c0 * HIDDEN + lane]);
            a1 += v1 * bf2f(x[(size_t)c1 * HIDDEN + lane]);
        }
        if (k < m) {
            int ck = __shfl(c, k); float vk = __shfl(v, k);
            a0 += vk * bf2f(x[(size_t)ck * HIDDEN + lane]);
        }
    }
    acc[(size_t)slot * HIDDEN + lane] += a0 + a1;
}

// ---------------- per-batch gather accumulate ----------------

// layer 0: fp32 source, init
__global__ void __launch_bounds__(256) k_gather0(const float* __restrict__ e,
                                                 const int* __restrict__ user,
                                                 const int* __restrict__ pos,
                                                 const int* __restrict__ neg,
                                                 int batch, float* __restrict__ acc) {
    int row  = (int)((blockIdx.x * blockDim.x + threadIdx.x) >> 6);
    int lane = threadIdx.x & 63;
    if (row >= 3 * batch) return;
    int which = row / batch, i = row - which * batch;
    const int* sel = (which == 0) ? user : (which == 1 ? pos : neg);
    int s = sel[i];
    acc[(size_t)row * HIDDEN + lane] = e[(size_t)s * HIDDEN + lane];
}

// layers 1..2: bf16 source, add
__global__ void __launch_bounds__(256) k_gather_bf(const ushort* __restrict__ e,
                                                   const int* __restrict__ user,
                                                   const int* __restrict__ pos,
                                                   const int* __restrict__ neg,
                                                   int batch, float* __restrict__ acc) {
    int row  = (int)((blockIdx.x * blockDim.x + threadIdx.x) >> 6);
    int lane = threadIdx.x & 63;
    if (row >= 3 * batch) return;
    int which = row / batch, i = row - which * batch;
    const int* sel = (which == 0) ? user : (which == 1 ? pos : neg);
    int s = sel[i];
    acc[(size_t)row * HIDDEN + lane] += bf2f(e[(size_t)s * HIDDEN + lane]);
}

// ---------------- loss ----------------

__global__ void __launch_bounds__(256) k_loss(const float* __restrict__ acc, int batch,
                                              float* __restrict__ out) {
    int i    = (int)((blockIdx.x * blockDim.x + threadIdx.x) >> 6);
    int lane = threadIdx.x & 63;
    if (i >= batch) return;
    float u  = acc[(size_t)i * HIDDEN + lane] * 0.25f;
    float p  = acc[(size_t)(i + batch) * HIDDEN + lane] * 0.25f;
    float nn = acc[(size_t)(i + 2 * batch) * HIDDEN + lane] * 0.25f;
    float sp = u * p, sn = u * nn;
    for (int d = 32; d > 0; d >>= 1) {
        sp += __shfl_down(sp, d);
        sn += __shfl_down(sn, d);
    }
    if (lane == 0) {
        float z = sn - sp;
        float loss = fmaxf(z, 0.f) + log1pf(expf(-fabsf(z)));
        atomicAdd(out, loss);
    }
}

// ---------------- orchestration ----------------

extern "C" void kernel_launch(void* const* d_in, const int* in_sizes, int n_in,
                              void* d_out, int out_size, void* d_ws, size_t ws_size,
                              hipStream_t stream) {
    (void)n_in; (void)out_size; (void)ws_size;
    const float* emb  = (const float*)d_in[0];
    const float* vals = (const float*)d_in[1];
    const int*   rows = (const int*)d_in[2];
    const int*   cols = (const int*)d_in[3];
    const int*   user = (const int*)d_in[4];
    const int*   pos  = (const int*)d_in[5];
    const int*   neg  = (const int*)d_in[6];

    const int n     = in_sizes[0] / HIDDEN;   // 150000
    const int nnz   = in_sizes[1];            // 4.8M
    const int batch = in_sizes[4];            // 4096

    auto align256 = [](size_t x) { return (x + 255) & ~(size_t)255; };
    char* w = (char*)d_ws;
    int*    cnt    = (int*)w;    w += align256(sizeof(int)    * (size_t)n);
    int*    off    = (int*)w;    w += align256(sizeof(int)    * (size_t)(n + 1));
    int2*   pack   = (int2*)w;   w += align256(sizeof(int2)   * (size_t)nnz);
    ushort* emb_bf = (ushort*)w; w += align256(sizeof(ushort) * (size_t)n * HIDDEN);
    ushort* e0     = (ushort*)w; w += align256(sizeof(ushort) * (size_t)n * HIDDEN);
    ushort* e1     = (ushort*)w; w += align256(sizeof(ushort) * (size_t)n * HIDDEN);
    float*  acc    = (float*)w;  w += align256(sizeof(float)  * (size_t)3 * batch * HIDDEN);
    int*    rank   = (int*)w;    w += align256(sizeof(int)    * (size_t)nnz);

    float* out = (float*)d_out;

    const int B = 256;
    dim3 blk(B);
    int g_nnz  = (nnz + B - 1) / B;
    int g_conv = (n * HIDDEN / 4 + B - 1) / B;
    int g_spmm = (n + 3) / 4;
    int g_gath = (3 * batch + 3) / 4;
    int g_loss = (batch + 3) / 4;

    // CSR build + bf16 conversion
    hipMemsetAsync(cnt, 0, sizeof(int) * (size_t)n, stream);
    k_hist<<<g_nnz, blk, 0, stream>>>(rows, cnt, rank, nnz);
    k_f2bf<<<g_conv, blk, 0, stream>>>((const float4*)emb, emb_bf, n * HIDDEN / 4);
    k_scan<<<1, 1024, 0, stream>>>(cnt, off, n);
    k_scatter<<<g_nnz, blk, 0, stream>>>(rows, cols, vals, off, rank, pack, nnz);

    hipMemsetAsync(out, 0, sizeof(float), stream);

    // layer 0
    k_gather0<<<g_gath, blk, 0, stream>>>(emb, user, pos, neg, batch, acc);
    // layer 1
    k_spmm<<<g_spmm, blk, 0, stream>>>(off, pack, emb_bf, e0, n);
    k_gather_bf<<<g_gath, blk, 0, stream>>>(e0, user, pos, neg, batch, acc);
    // layer 2
    k_spmm<<<g_spmm, blk, 0, stream>>>(off, pack, e0, e1, n);
    k_gather_bf<<<g_gath, blk, 0, stream>>>(e1, user, pos, neg, batch, acc);
    // layer 3 (fused selective SpMM + accumulate)
    k_spmm_batch<<<g_gath, blk, 0, stream>>>(off, pack, e1, user, pos, neg, batch, acc);

    k_loss<<<g_loss, blk, 0, stream>>>(acc, batch, out);
}

// Round 4
// 590.401 us; speedup vs baseline: 2.7756x; 1.5243x over previous
//
#include <hip/hip_runtime.h>

#define HIDDEN 64
#define SCAN_B 256

typedef unsigned int uint;

__device__ __forceinline__ ushort f2bf(float f) {
    uint u = __float_as_uint(f);
    u = (u + 0x7FFFu + ((u >> 16) & 1u)) >> 16;   // round-to-nearest-even
    return (ushort)u;
}
__device__ __forceinline__ float bf2f(ushort h) {
    return __uint_as_float(((uint)h) << 16);
}

// ---------------- fp32 -> bf16 table conversion ----------------

__global__ void __launch_bounds__(256) k_f2bf(const float4* __restrict__ src,
                                              ushort* __restrict__ dst, int n4) {
    int i = blockIdx.x * blockDim.x + threadIdx.x;
    if (i >= n4) return;
    float4 f = src[i];
    ushort4 o;
    o.x = f2bf(f.x); o.y = f2bf(f.y); o.z = f2bf(f.z); o.w = f2bf(f.w);
    ((ushort4*)dst)[i] = o;
}

// ---------------- CSR build ----------------

__global__ void k_hist(const int* __restrict__ rows, int* __restrict__ cnt,
                       int* __restrict__ rank, int nnz) {
    int i = blockIdx.x * blockDim.x + threadIdx.x;
    if (i < nnz) rank[i] = atomicAdd(&cnt[rows[i]], 1);
}

// ---- multi-block scan: (1) block sums, (2) scan of block sums, (3) output ----

__global__ void __launch_bounds__(SCAN_B) k_scan1(const int* __restrict__ cnt,
                                                  int* __restrict__ bsum, int n) {
    int i = blockIdx.x * SCAN_B + threadIdx.x;
    int v = (i < n) ? cnt[i] : 0;
    for (int d = 1; d < 64; d <<= 1) v += __shfl_xor(v, d);
    __shared__ int ws[SCAN_B / 64];
    int lane = threadIdx.x & 63, wid = threadIdx.x >> 6;
    if (lane == 0) ws[wid] = v;
    __syncthreads();
    if (threadIdx.x == 0) {
        int s = 0;
        #pragma unroll
        for (int k = 0; k < SCAN_B / 64; ++k) s += ws[k];
        bsum[blockIdx.x] = s;
    }
}

// single block over nb (<=1024) partials; writes exclusive boff and off[n]=total
__global__ void __launch_bounds__(1024) k_scan2(const int* __restrict__ bsum,
                                                int* __restrict__ boff,
                                                int* __restrict__ off, int nb, int n) {
    __shared__ int sums[1024];
    int t = threadIdx.x;
    int v = (t < nb) ? bsum[t] : 0;
    sums[t] = v;
    __syncthreads();
    for (int d = 1; d < 1024; d <<= 1) {
        int p = (t >= d) ? sums[t - d] : 0;
        __syncthreads();
        sums[t] += p;
        __syncthreads();
    }
    if (t < nb) boff[t] = sums[t] - v;      // exclusive prefix of block t
    if (t == 1023) off[n] = sums[1023];     // grand total
}

__global__ void __launch_bounds__(SCAN_B) k_scan3(const int* __restrict__ cnt,
                                                  const int* __restrict__ boff,
                                                  int* __restrict__ off, int n) {
    int i = blockIdx.x * SCAN_B + threadIdx.x;
    int v = (i < n) ? cnt[i] : 0;
    int lane = threadIdx.x & 63, wid = threadIdx.x >> 6;
    // wave-inclusive scan
    int inc = v;
    for (int d = 1; d < 64; d <<= 1) {
        int t = __shfl_up(inc, d);
        if (lane >= d) inc += t;
    }
    __shared__ int wsum[SCAN_B / 64];
    if (lane == 63) wsum[wid] = inc;
    __syncthreads();
    int woff = 0;
    #pragma unroll
    for (int k = 0; k < SCAN_B / 64; ++k) woff += (k < wid) ? wsum[k] : 0;
    if (i < n) off[i] = boff[blockIdx.x] + woff + (inc - v);
}

__global__ void k_scatter(const int* __restrict__ rows, const int* __restrict__ cols,
                          const float* __restrict__ vals, const int* __restrict__ off,
                          const int* __restrict__ rank, int2* __restrict__ pack, int nnz) {
    int i = blockIdx.x * blockDim.x + threadIdx.x;
    if (i >= nnz) return;
    int r = rows[i];
    int p = off[r] + rank[i];
    pack[p] = make_int2(cols[i], __float_as_int(vals[i]));
}

// ---------------- SpMM (bf16 x, bf16 y, fp32 accumulate, 4-way ILP) ----------------

__device__ __forceinline__ float spmm_row(const int* __restrict__ off,
                                          const int2* __restrict__ pack,
                                          const ushort* __restrict__ x,
                                          int row, int lane) {
    int start = off[row], end = off[row + 1];
    float a0 = 0.f, a1 = 0.f, a2 = 0.f, a3 = 0.f;
    for (int j0 = start; j0 < end; j0 += 64) {
        int m = end - j0; if (m > 64) m = 64;
        int   c = 0;
        float v = 0.f;
        if (lane < m) {
            int2 cv = pack[j0 + lane];
            c = cv.x;
            v = __int_as_float(cv.y);
        }
        int k = 0;
        for (; k + 3 < m; k += 4) {
            int   c0 = __shfl(c, k);     float v0 = __shfl(v, k);
            int   c1 = __shfl(c, k + 1); float v1 = __shfl(v, k + 1);
            int   c2 = __shfl(c, k + 2); float v2 = __shfl(v, k + 2);
            int   c3 = __shfl(c, k + 3); float v3 = __shfl(v, k + 3);
            a0 += v0 * bf2f(x[(size_t)c0 * HIDDEN + lane]);
            a1 += v1 * bf2f(x[(size_t)c1 * HIDDEN + lane]);
            a2 += v2 * bf2f(x[(size_t)c2 * HIDDEN + lane]);
            a3 += v3 * bf2f(x[(size_t)c3 * HIDDEN + lane]);
        }
        for (; k < m; ++k) {
            int ck = __shfl(c, k); float vk = __shfl(v, k);
            a0 += vk * bf2f(x[(size_t)ck * HIDDEN + lane]);
        }
    }
    return (a0 + a1) + (a2 + a3);
}

__global__ void __launch_bounds__(256) k_spmm(const int* __restrict__ off,
                                              const int2* __restrict__ pack,
                                              const ushort* __restrict__ x,
                                              ushort* __restrict__ y, int n) {
    int row  = (int)((blockIdx.x * blockDim.x + threadIdx.x) >> 6);
    int lane = threadIdx.x & 63;
    if (row >= n) return;
    y[(size_t)row * HIDDEN + lane] = f2bf(spmm_row(off, pack, x, row, lane));
}

// final layer fused: SpMM restricted to batch rows, accumulate fp32 into acc
__global__ void __launch_bounds__(256) k_spmm_batch(const int* __restrict__ off,
                                                    const int2* __restrict__ pack,
                                                    const ushort* __restrict__ x,
                                                    const int* __restrict__ user,
                                                    const int* __restrict__ pos,
                                                    const int* __restrict__ neg,
                                                    int batch, float* __restrict__ acc) {
    int slot = (int)((blockIdx.x * blockDim.x + threadIdx.x) >> 6);
    int lane = threadIdx.x & 63;
    if (slot >= 3 * batch) return;
    int which = slot / batch, i = slot - which * batch;
    const int* sel = (which == 0) ? user : (which == 1 ? pos : neg);
    acc[(size_t)slot * HIDDEN + lane] += spmm_row(off, pack, x, sel[i], lane);
}

// ---------------- per-batch gather accumulate ----------------

__global__ void __launch_bounds__(256) k_gather0(const float* __restrict__ e,
                                                 const int* __restrict__ user,
                                                 const int* __restrict__ pos,
                                                 const int* __restrict__ neg,
                                                 int batch, float* __restrict__ acc) {
    int row  = (int)((blockIdx.x * blockDim.x + threadIdx.x) >> 6);
    int lane = threadIdx.x & 63;
    if (row >= 3 * batch) return;
    int which = row / batch, i = row - which * batch;
    const int* sel = (which == 0) ? user : (which == 1 ? pos : neg);
    int s = sel[i];
    acc[(size_t)row * HIDDEN + lane] = e[(size_t)s * HIDDEN + lane];
}

__global__ void __launch_bounds__(256) k_gather_bf(const ushort* __restrict__ e,
                                                   const int* __restrict__ user,
                                                   const int* __restrict__ pos,
                                                   const int* __restrict__ neg,
                                                   int batch, float* __restrict__ acc) {
    int row  = (int)((blockIdx.x * blockDim.x + threadIdx.x) >> 6);
    int lane = threadIdx.x & 63;
    if (row >= 3 * batch) return;
    int which = row / batch, i = row - which * batch;
    const int* sel = (which == 0) ? user : (which == 1 ? pos : neg);
    int s = sel[i];
    acc[(size_t)row * HIDDEN + lane] += bf2f(e[(size_t)s * HIDDEN + lane]);
}

// ---------------- loss ----------------

__global__ void __launch_bounds__(256) k_loss(const float* __restrict__ acc, int batch,
                                              float* __restrict__ out) {
    int i    = (int)((blockIdx.x * blockDim.x + threadIdx.x) >> 6);
    int lane = threadIdx.x & 63;
    if (i >= batch) return;
    float u  = acc[(size_t)i * HIDDEN + lane] * 0.25f;
    float p  = acc[(size_t)(i + batch) * HIDDEN + lane] * 0.25f;
    float nn = acc[(size_t)(i + 2 * batch) * HIDDEN + lane] * 0.25f;
    float sp = u * p, sn = u * nn;
    for (int d = 32; d > 0; d >>= 1) {
        sp += __shfl_down(sp, d);
        sn += __shfl_down(sn, d);
    }
    if (lane == 0) {
        float z = sn - sp;
        float loss = fmaxf(z, 0.f) + log1pf(expf(-fabsf(z)));
        atomicAdd(out, loss);
    }
}

// ---------------- orchestration ----------------

extern "C" void kernel_launch(void* const* d_in, const int* in_sizes, int n_in,
                              void* d_out, int out_size, void* d_ws, size_t ws_size,
                              hipStream_t stream) {
    (void)n_in; (void)out_size; (void)ws_size;
    const float* emb  = (const float*)d_in[0];
    const float* vals = (const float*)d_in[1];
    const int*   rows = (const int*)d_in[2];
    const int*   cols = (const int*)d_in[3];
    const int*   user = (const int*)d_in[4];
    const int*   pos  = (const int*)d_in[5];
    const int*   neg  = (const int*)d_in[6];

    const int n     = in_sizes[0] / HIDDEN;   // 150000
    const int nnz   = in_sizes[1];            // 4.8M
    const int batch = in_sizes[4];            // 4096

    auto align256 = [](size_t x) { return (x + 255) & ~(size_t)255; };
    char* w = (char*)d_ws;
    int*    cnt    = (int*)w;    w += align256(sizeof(int)    * (size_t)n);
    int*    off    = (int*)w;    w += align256(sizeof(int)    * (size_t)(n + 1));
    int*    bsum   = (int*)w;    w += align256(sizeof(int)    * 1024);
    int*    boff   = (int*)w;    w += align256(sizeof(int)    * 1024);
    int2*   pack   = (int2*)w;   w += align256(sizeof(int2)   * (size_t)nnz);
    ushort* emb_bf = (ushort*)w; w += align256(sizeof(ushort) * (size_t)n * HIDDEN);
    ushort* e0     = (ushort*)w; w += align256(sizeof(ushort) * (size_t)n * HIDDEN);
    ushort* e1     = (ushort*)w; w += align256(sizeof(ushort) * (size_t)n * HIDDEN);
    float*  acc    = (float*)w;  w += align256(sizeof(float)  * (size_t)3 * batch * HIDDEN);
    int*    rank   = (int*)w;    w += align256(sizeof(int)    * (size_t)nnz);

    float* out = (float*)d_out;

    const int B = 256;
    dim3 blk(B);
    int g_nnz  = (nnz + B - 1) / B;
    int g_conv = (n * HIDDEN / 4 + B - 1) / B;
    int g_scan = (n + SCAN_B - 1) / SCAN_B;   // 586 blocks
    int g_spmm = (n + 3) / 4;
    int g_gath = (3 * batch + 3) / 4;
    int g_loss = (batch + 3) / 4;

    // CSR build + bf16 conversion
    hipMemsetAsync(cnt, 0, sizeof(int) * (size_t)n, stream);
    k_hist<<<g_nnz, blk, 0, stream>>>(rows, cnt, rank, nnz);
    k_f2bf<<<g_conv, blk, 0, stream>>>((const float4*)emb, emb_bf, n * HIDDEN / 4);
    k_scan1<<<g_scan, SCAN_B, 0, stream>>>(cnt, bsum, n);
    k_scan2<<<1, 1024, 0, stream>>>(bsum, boff, off, g_scan, n);
    k_scan3<<<g_scan, SCAN_B, 0, stream>>>(cnt, boff, off, n);
    k_scatter<<<g_nnz, blk, 0, stream>>>(rows, cols, vals, off, rank, pack, nnz);

    hipMemsetAsync(out, 0, sizeof(float), stream);

    // layer 0
    k_gather0<<<g_gath, blk, 0, stream>>>(emb, user, pos, neg, batch, acc);
    // layer 1
    k_spmm<<<g_spmm, blk, 0, stream>>>(off, pack, emb_bf, e0, n);
    k_gather_bf<<<g_gath, blk, 0, stream>>>(e0, user, pos, neg, batch, acc);
    // layer 2
    k_spmm<<<g_spmm, blk, 0, stream>>>(off, pack, e0, e1, n);
    k_gather_bf<<<g_gath, blk, 0, stream>>>(e1, user, pos, neg, batch, acc);
    // layer 3 (fused selective SpMM + accumulate)
    k_spmm_batch<<<g_gath, blk, 0, stream>>>(off, pack, e1, user, pos, neg, batch, acc);

    k_loss<<<g_loss, blk, 0, stream>>>(acc, batch, out);
}

// Round 5
// 582.028 us; speedup vs baseline: 2.8155x; 1.0144x over previous
//
#include <hip/hip_runtime.h>

#define HIDDEN 64
#define SCAN_B 256
#define NREP 8

typedef unsigned int uint;

__device__ __forceinline__ ushort f2bf(float f) {
    uint u = __float_as_uint(f);
    u = (u + 0x7FFFu + ((u >> 16) & 1u)) >> 16;   // round-to-nearest-even
    return (ushort)u;
}
__device__ __forceinline__ float bf2f(ushort h) {
    return __uint_as_float(((uint)h) << 16);
}

// ---------------- fp32 -> bf16 table conversion ----------------

__global__ void __launch_bounds__(256) k_f2bf(const float4* __restrict__ src,
                                              ushort* __restrict__ dst, int n4) {
    int i = blockIdx.x * blockDim.x + threadIdx.x;
    if (i >= n4) return;
    float4 f = src[i];
    ushort4 o;
    o.x = f2bf(f.x); o.y = f2bf(f.y); o.z = f2bf(f.z); o.w = f2bf(f.w);
    ((ushort4*)dst)[i] = o;
}

// ---------------- CSR build ----------------
// Histogram into 8 per-XCD replicas (replica = blockIdx&7 matches round-robin
// block->XCD dispatch; pure perf heuristic, any mapping stays correct).
// 4 edges per thread for MLP.

__global__ void __launch_bounds__(256) k_hist(const int* __restrict__ rows,
                                              int* __restrict__ cnt8,
                                              int* __restrict__ rank, int nnz, int n) {
    int t = blockIdx.x * blockDim.x + threadIdx.x;
    int i = t * 4;
    int rep = (blockIdx.x & (NREP - 1)) * n;
    if (i + 3 < nnz) {
        int4 r4 = *(const int4*)(rows + i);
        int4 k4;
        k4.x = atomicAdd(&cnt8[rep + r4.x], 1);
        k4.y = atomicAdd(&cnt8[rep + r4.y], 1);
        k4.z = atomicAdd(&cnt8[rep + r4.z], 1);
        k4.w = atomicAdd(&cnt8[rep + r4.w], 1);
        *(int4*)(rank + i) = k4;
    } else {
        for (; i < nnz; ++i) rank[i] = atomicAdd(&cnt8[rep + rows[i]], 1);
    }
}

// row totals for the scan
__global__ void __launch_bounds__(256) k_fold_a(const int* __restrict__ cnt8,
                                                int* __restrict__ cnt, int n) {
    int r = blockIdx.x * blockDim.x + threadIdx.x;
    if (r >= n) return;
    int run = 0;
    #pragma unroll
    for (int c = 0; c < NREP; ++c) run += cnt8[c * n + r];
    cnt[r] = run;
}

// per-replica absolute row starts: rowstart8[c][r] = off[r] + sum_{c'<c} cnt8[c'][r]
__global__ void __launch_bounds__(256) k_fold_b(const int* __restrict__ cnt8,
                                                const int* __restrict__ off,
                                                int* __restrict__ rowstart8, int n) {
    int r = blockIdx.x * blockDim.x + threadIdx.x;
    if (r >= n) return;
    int run = off[r];
    #pragma unroll
    for (int c = 0; c < NREP; ++c) {
        rowstart8[c * n + r] = run;
        run += cnt8[c * n + r];
    }
}

// ---- multi-block scan ----

__global__ void __launch_bounds__(SCAN_B) k_scan1(const int* __restrict__ cnt,
                                                  int* __restrict__ bsum, int n) {
    int i = blockIdx.x * SCAN_B + threadIdx.x;
    int v = (i < n) ? cnt[i] : 0;
    for (int d = 1; d < 64; d <<= 1) v += __shfl_xor(v, d);
    __shared__ int ws[SCAN_B / 64];
    int lane = threadIdx.x & 63, wid = threadIdx.x >> 6;
    if (lane == 0) ws[wid] = v;
    __syncthreads();
    if (threadIdx.x == 0) {
        int s = 0;
        #pragma unroll
        for (int k = 0; k < SCAN_B / 64; ++k) s += ws[k];
        bsum[blockIdx.x] = s;
    }
}

__global__ void __launch_bounds__(1024) k_scan2(const int* __restrict__ bsum,
                                                int* __restrict__ boff,
                                                int* __restrict__ off, int nb, int n) {
    __shared__ int sums[1024];
    int t = threadIdx.x;
    int v = (t < nb) ? bsum[t] : 0;
    sums[t] = v;
    __syncthreads();
    for (int d = 1; d < 1024; d <<= 1) {
        int p = (t >= d) ? sums[t - d] : 0;
        __syncthreads();
        sums[t] += p;
        __syncthreads();
    }
    if (t < nb) boff[t] = sums[t] - v;
    if (t == 1023) off[n] = sums[1023];
}

__global__ void __launch_bounds__(SCAN_B) k_scan3(const int* __restrict__ cnt,
                                                  const int* __restrict__ boff,
                                                  int* __restrict__ off, int n) {
    int i = blockIdx.x * SCAN_B + threadIdx.x;
    int v = (i < n) ? cnt[i] : 0;
    int lane = threadIdx.x & 63, wid = threadIdx.x >> 6;
    int inc = v;
    for (int d = 1; d < 64; d <<= 1) {
        int t = __shfl_up(inc, d);
        if (lane >= d) inc += t;
    }
    __shared__ int wsum[SCAN_B / 64];
    if (lane == 63) wsum[wid] = inc;
    __syncthreads();
    int woff = 0;
    #pragma unroll
    for (int k = 0; k < SCAN_B / 64; ++k) woff += (k < wid) ? wsum[k] : 0;
    if (i < n) off[i] = boff[blockIdx.x] + woff + (inc - v);
}

// scatter: 4 edges/thread, replica mapping identical to k_hist
__global__ void __launch_bounds__(256) k_scatter(const int* __restrict__ rows,
                                                 const int* __restrict__ cols,
                                                 const float* __restrict__ vals,
                                                 const int* __restrict__ rowstart8,
                                                 const int* __restrict__ rank,
                                                 int2* __restrict__ pack, int nnz, int n) {
    int t = blockIdx.x * blockDim.x + threadIdx.x;
    int i = t * 4;
    int rep = (blockIdx.x & (NREP - 1)) * n;
    if (i + 3 < nnz) {
        int4   r4 = *(const int4*)(rows + i);
        int4   c4 = *(const int4*)(cols + i);
        float4 v4 = *(const float4*)(vals + i);
        int4   k4 = *(const int4*)(rank + i);
        pack[rowstart8[rep + r4.x] + k4.x] = make_int2(c4.x, __float_as_int(v4.x));
        pack[rowstart8[rep + r4.y] + k4.y] = make_int2(c4.y, __float_as_int(v4.y));
        pack[rowstart8[rep + r4.z] + k4.z] = make_int2(c4.z, __float_as_int(v4.z));
        pack[rowstart8[rep + r4.w] + k4.w] = make_int2(c4.w, __float_as_int(v4.w));
    } else {
        for (; i < nnz; ++i) {
            int r = rows[i];
            pack[rowstart8[rep + r] + rank[i]] = make_int2(cols[i], __float_as_int(vals[i]));
        }
    }
}

// ---------------- SpMM (bf16 x, fp32 accumulate, 8-deep gather pipeline) ----------------

__device__ __forceinline__ float spmm_row(const int* __restrict__ off,
                                          const int2* __restrict__ pack,
                                          const ushort* __restrict__ x,
                                          int row, int lane) {
    int start = off[row], end = off[row + 1];
    float a0 = 0.f, a1 = 0.f, a2 = 0.f, a3 = 0.f;
    for (int j0 = start; j0 < end; j0 += 64) {
        int m = end - j0; if (m > 64) m = 64;
        int   c = 0;
        float v = 0.f;
        if (lane < m) {
            int2 cv = pack[j0 + lane];
            c = cv.x;
            v = __int_as_float(cv.y);
        }
        int k = 0;
        for (; k + 7 < m; k += 8) {
            int c0 = __shfl(c, k);     int c1 = __shfl(c, k + 1);
            int c2 = __shfl(c, k + 2); int c3 = __shfl(c, k + 3);
            int c4 = __shfl(c, k + 4); int c5 = __shfl(c, k + 5);
            int c6 = __shfl(c, k + 6); int c7 = __shfl(c, k + 7);
            float v0 = __shfl(v, k);     float v1 = __shfl(v, k + 1);
            float v2 = __shfl(v, k + 2); float v3 = __shfl(v, k + 3);
            float v4 = __shfl(v, k + 4); float v5 = __shfl(v, k + 5);
            float v6 = __shfl(v, k + 6); float v7 = __shfl(v, k + 7);
            float x0 = bf2f(x[(size_t)c0 * HIDDEN + lane]);
            float x1 = bf2f(x[(size_t)c1 * HIDDEN + lane]);
            float x2 = bf2f(x[(size_t)c2 * HIDDEN + lane]);
            float x3 = bf2f(x[(size_t)c3 * HIDDEN + lane]);
            float x4 = bf2f(x[(size_t)c4 * HIDDEN + lane]);
            float x5 = bf2f(x[(size_t)c5 * HIDDEN + lane]);
            float x6 = bf2f(x[(size_t)c6 * HIDDEN + lane]);
            float x7 = bf2f(x[(size_t)c7 * HIDDEN + lane]);
            a0 += v0 * x0; a1 += v1 * x1; a2 += v2 * x2; a3 += v3 * x3;
            a0 += v4 * x4; a1 += v5 * x5; a2 += v6 * x6; a3 += v7 * x7;
        }
        for (; k < m; ++k) {
            int ck = __shfl(c, k); float vk = __shfl(v, k);
            a0 += vk * bf2f(x[(size_t)ck * HIDDEN + lane]);
        }
    }
    return (a0 + a1) + (a2 + a3);
}

__global__ void __launch_bounds__(256) k_spmm(const int* __restrict__ off,
                                              const int2* __restrict__ pack,
                                              const ushort* __restrict__ x,
                                              ushort* __restrict__ y, int n) {
    int row  = (int)((blockIdx.x * blockDim.x + threadIdx.x) >> 6);
    int lane = threadIdx.x & 63;
    if (row >= n) return;
    y[(size_t)row * HIDDEN + lane] = f2bf(spmm_row(off, pack, x, row, lane));
}

__global__ void __launch_bounds__(256) k_spmm_batch(const int* __restrict__ off,
                                                    const int2* __restrict__ pack,
                                                    const ushort* __restrict__ x,
                                                    const int* __restrict__ user,
                                                    const int* __restrict__ pos,
                                                    const int* __restrict__ neg,
                                                    int batch, float* __restrict__ acc) {
    int slot = (int)((blockIdx.x * blockDim.x + threadIdx.x) >> 6);
    int lane = threadIdx.x & 63;
    if (slot >= 3 * batch) return;
    int which = slot / batch, i = slot - which * batch;
    const int* sel = (which == 0) ? user : (which == 1 ? pos : neg);
    acc[(size_t)slot * HIDDEN + lane] += spmm_row(off, pack, x, sel[i], lane);
}

// ---------------- per-batch gather accumulate ----------------

__global__ void __launch_bounds__(256) k_gather0(const float* __restrict__ e,
                                                 const int* __restrict__ user,
                                                 const int* __restrict__ pos,
                                                 const int* __restrict__ neg,
                                                 int batch, float* __restrict__ acc) {
    int row  = (int)((blockIdx.x * blockDim.x + threadIdx.x) >> 6);
    int lane = threadIdx.x & 63;
    if (row >= 3 * batch) return;
    int which = row / batch, i = row - which * batch;
    const int* sel = (which == 0) ? user : (which == 1 ? pos : neg);
    int s = sel[i];
    acc[(size_t)row * HIDDEN + lane] = e[(size_t)s * HIDDEN + lane];
}

__global__ void __launch_bounds__(256) k_gather_bf(const ushort* __restrict__ e,
                                                   const int* __restrict__ user,
                                                   const int* __restrict__ pos,
                                                   const int* __restrict__ neg,
                                                   int batch, float* __restrict__ acc) {
    int row  = (int)((blockIdx.x * blockDim.x + threadIdx.x) >> 6);
    int lane = threadIdx.x & 63;
    if (row >= 3 * batch) return;
    int which = row / batch, i = row - which * batch;
    const int* sel = (which == 0) ? user : (which == 1 ? pos : neg);
    int s = sel[i];
    acc[(size_t)row * HIDDEN + lane] += bf2f(e[(size_t)s * HIDDEN + lane]);
}

// ---------------- loss ----------------

__global__ void __launch_bounds__(256) k_loss(const float* __restrict__ acc, int batch,
                                              float* __restrict__ out) {
    int i    = (int)((blockIdx.x * blockDim.x + threadIdx.x) >> 6);
    int lane = threadIdx.x & 63;
    if (i >= batch) return;
    float u  = acc[(size_t)i * HIDDEN + lane] * 0.25f;
    float p  = acc[(size_t)(i + batch) * HIDDEN + lane] * 0.25f;
    float nn = acc[(size_t)(i + 2 * batch) * HIDDEN + lane] * 0.25f;
    float sp = u * p, sn = u * nn;
    for (int d = 32; d > 0; d >>= 1) {
        sp += __shfl_down(sp, d);
        sn += __shfl_down(sn, d);
    }
    if (lane == 0) {
        float z = sn - sp;
        float loss = fmaxf(z, 0.f) + log1pf(expf(-fabsf(z)));
        atomicAdd(out, loss);
    }
}

// ---------------- orchestration ----------------

extern "C" void kernel_launch(void* const* d_in, const int* in_sizes, int n_in,
                              void* d_out, int out_size, void* d_ws, size_t ws_size,
                              hipStream_t stream) {
    (void)n_in; (void)out_size; (void)ws_size;
    const float* emb  = (const float*)d_in[0];
    const float* vals = (const float*)d_in[1];
    const int*   rows = (const int*)d_in[2];
    const int*   cols = (const int*)d_in[3];
    const int*   user = (const int*)d_in[4];
    const int*   pos  = (const int*)d_in[5];
    const int*   neg  = (const int*)d_in[6];

    const int n     = in_sizes[0] / HIDDEN;   // 150000
    const int nnz   = in_sizes[1];            // 4.8M
    const int batch = in_sizes[4];            // 4096

    auto align256 = [](size_t x) { return (x + 255) & ~(size_t)255; };
    char* w = (char*)d_ws;
    int*    cnt    = (int*)w;    w += align256(sizeof(int)    * (size_t)n);
    int*    off    = (int*)w;    w += align256(sizeof(int)    * (size_t)(n + 1));
    int*    bsum   = (int*)w;    w += align256(sizeof(int)    * 1024);
    int*    boff   = (int*)w;    w += align256(sizeof(int)    * 1024);
    int2*   pack   = (int2*)w;   w += align256(sizeof(int2)   * (size_t)nnz);
    ushort* emb_bf = (ushort*)w; w += align256(sizeof(ushort) * (size_t)n * HIDDEN);
    ushort* e0     = (ushort*)w; w += align256(sizeof(ushort) * (size_t)n * HIDDEN);
    ushort* e1     = (ushort*)w; w += align256(sizeof(ushort) * (size_t)n * HIDDEN);
    float*  acc    = (float*)w;  w += align256(sizeof(float)  * (size_t)3 * batch * HIDDEN);
    int*    rank   = (int*)w;    w += align256(sizeof(int)    * (size_t)nnz);

    // replica state lives in e0's region: only needed before layer-1 SpMM writes e0.
    // cnt8: NREP*n ints (4.8MB) + rowstart8: NREP*n ints (4.8MB) <= 19.2MB of e0.
    int* cnt8      = (int*)e0;
    int* rowstart8 = (int*)e0 + (size_t)NREP * n;

    float* out = (float*)d_out;

    const int B = 256;
    dim3 blk(B);
    int g_edge4 = ((nnz + 3) / 4 + B - 1) / B;   // 4 edges per thread
    int g_conv  = (n * HIDDEN / 4 + B - 1) / B;
    int g_scan  = (n + SCAN_B - 1) / SCAN_B;
    int g_row   = (n + B - 1) / B;
    int g_spmm  = (n + 3) / 4;
    int g_gath  = (3 * batch + 3) / 4;
    int g_loss  = (batch + 3) / 4;

    // CSR build + bf16 conversion
    hipMemsetAsync(cnt8, 0, sizeof(int) * (size_t)NREP * n, stream);
    k_hist<<<g_edge4, blk, 0, stream>>>(rows, cnt8, rank, nnz, n);
    k_f2bf<<<g_conv, blk, 0, stream>>>((const float4*)emb, emb_bf, n * HIDDEN / 4);
    k_fold_a<<<g_row, blk, 0, stream>>>(cnt8, cnt, n);
    k_scan1<<<g_scan, SCAN_B, 0, stream>>>(cnt, bsum, n);
    k_scan2<<<1, 1024, 0, stream>>>(bsum, boff, off, g_scan, n);
    k_scan3<<<g_scan, SCAN_B, 0, stream>>>(cnt, boff, off, n);
    k_fold_b<<<g_row, blk, 0, stream>>>(cnt8, off, rowstart8, n);
    k_scatter<<<g_edge4, blk, 0, stream>>>(rows, cols, vals, rowstart8, rank, pack, nnz, n);

    hipMemsetAsync(out, 0, sizeof(float), stream);

    // layer 0
    k_gather0<<<g_gath, blk, 0, stream>>>(emb, user, pos, neg, batch, acc);
    // layer 1
    k_spmm<<<g_spmm, blk, 0, stream>>>(off, pack, emb_bf, e0, n);
    k_gather_bf<<<g_gath, blk, 0, stream>>>(e0, user, pos, neg, batch, acc);
    // layer 2
    k_spmm<<<g_spmm, blk, 0, stream>>>(off, pack, e0, e1, n);
    k_gather_bf<<<g_gath, blk, 0, stream>>>(e1, user, pos, neg, batch, acc);
    // layer 3 (fused selective SpMM + accumulate)
    k_spmm_batch<<<g_gath, blk, 0, stream>>>(off, pack, e1, user, pos, neg, batch, acc);

    k_loss<<<g_loss, blk, 0, stream>>>(acc, batch, out);
}